// Round 3
// baseline (221.607 us; speedup 1.0000x reference)
//
#include <hip/hip_runtime.h>

// DualCompressor: y_fwd[v,m] = log(sum_k exp(d_out_t[v,k] + alpha_fwd[m,k]))
//                 y_bwd[v,m] = log(sum_k exp(d_in_t[v,k]  + alpha_bwd[m,k]))
// SIGMA = 1.0.
//
// log(sum_k exp(phi_k)*exp(alpha_mk)): exp(alpha) in LDS, exp(phi) in regs,
// 16 FMA dot products per row.
//
// R2 change: 2 rows per thread. R1 was LDS-issue-bound: 256 ds_read_b128 per
// wave per 64 rows at ~12 cyc/CU each = 15.6 us/CU (matches measured 15.9 us
// kernel time). Sharing each wave-uniform LDS read across 2 rows halves that
// to 7.8 us, below the 10.2 us HBM floor (64 MB @ 6.3 TB/s) -> memory-bound.
//
// Mapping: block 256 = 4 waves covering 256 rows; wave w: c = w&1
// (0=fwd, 1=bwd), rh = w>>1; rows = bid*256 + rh*128 + lane (+64).
// All ealpha LDS reads wave-uniform -> HW broadcast, zero bank conflicts.

#define K_DIM 64

__global__ __launch_bounds__(256) void dual_compress_kernel(
    const float* __restrict__ d_out_t,
    const float* __restrict__ d_in_t,
    const float* __restrict__ alpha_fwd,
    const float* __restrict__ alpha_bwd,
    float* __restrict__ out, int V)
{
    // exp(alpha): [c][m][k], c=0 fwd rows 0..15, c=1 bwd rows 16..31
    __shared__ float ealpha[32 * K_DIM];

    int tid = threadIdx.x;
    #pragma unroll
    for (int it = 0; it < 8; ++it) {
        int i = tid + it * 256;                       // 0..2047
        float a = (i < 1024) ? alpha_fwd[i] : alpha_bwd[i - 1024];
        ealpha[i] = __expf(a);
    }
    __syncthreads();

    int lane = tid & 63;
    int w    = tid >> 6;        // wave id: 0..3
    int c    = w & 1;           // 0 = fwd (d_out_t), 1 = bwd (d_in_t)
    int rh   = w >> 1;          // row group within the block's 256 rows
    int v0   = blockIdx.x * 256 + rh * 128 + lane;
    int v1   = v0 + 64;
    if (v0 >= V) return;
    bool has1 = (v1 < V);

    const float* base = (c == 0) ? d_out_t : d_in_t;
    const float* phi0 = base + (size_t)v0 * K_DIM;
    const float* phi1 = base + (size_t)(has1 ? v1 : v0) * K_DIM;  // safe addr

    // exp(phi rows) into registers (2 x 16 x float4 = 128 VGPRs)
    float4 e0[16], e1[16];
    #pragma unroll
    for (int i = 0; i < 16; ++i) {
        float4 p = ((const float4*)phi0)[i];
        float4 q = ((const float4*)phi1)[i];
        e0[i].x = __expf(p.x); e0[i].y = __expf(p.y);
        e0[i].z = __expf(p.z); e0[i].w = __expf(p.w);
        e1[i].x = __expf(q.x); e1[i].y = __expf(q.y);
        e1[i].z = __expf(q.z); e1[i].w = __expf(q.w);
    }

    // 16 dot products x 2 rows against wave-uniform LDS rows
    const float4* arow_base = (const float4*)&ealpha[c * 16 * K_DIM];

    float y0[16], y1[16];
    #pragma unroll
    for (int mi = 0; mi < 16; ++mi) {
        const float4* a4 = arow_base + mi * 16;
        float acc0 = 0.0f, acc1 = 0.0f;
        #pragma unroll
        for (int k = 0; k < 16; ++k) {
            float4 a = a4[k];
            acc0 = fmaf(e0[k].x, a.x, acc0);
            acc0 = fmaf(e0[k].y, a.y, acc0);
            acc0 = fmaf(e0[k].z, a.z, acc0);
            acc0 = fmaf(e0[k].w, a.w, acc0);
            acc1 = fmaf(e1[k].x, a.x, acc1);
            acc1 = fmaf(e1[k].y, a.y, acc1);
            acc1 = fmaf(e1[k].z, a.z, acc1);
            acc1 = fmaf(e1[k].w, a.w, acc1);
        }
        y0[mi] = __logf(acc0);
        y1[mi] = __logf(acc1);
    }

    // output: y_fwd (V x 16) then y_bwd (V x 16)
    float* orow0 = out + ((size_t)c * V + v0) * 16;
    #pragma unroll
    for (int i = 0; i < 4; ++i)
        ((float4*)orow0)[i] = make_float4(y0[4*i], y0[4*i+1], y0[4*i+2], y0[4*i+3]);

    if (has1) {
        float* orow1 = out + ((size_t)c * V + v1) * 16;
        #pragma unroll
        for (int i = 0; i < 4; ++i)
            ((float4*)orow1)[i] = make_float4(y1[4*i], y1[4*i+1], y1[4*i+2], y1[4*i+3]);
    }
}

extern "C" void kernel_launch(void* const* d_in, const int* in_sizes, int n_in,
                              void* d_out, int out_size, void* d_ws, size_t ws_size,
                              hipStream_t stream) {
    const float* d_out_t   = (const float*)d_in[0];
    const float* d_in_t    = (const float*)d_in[1];
    const float* alpha_fwd = (const float*)d_in[2];
    const float* alpha_bwd = (const float*)d_in[3];
    float* out = (float*)d_out;

    int V = in_sizes[0] / K_DIM;          // 100000
    int grid = (V + 255) / 256;           // 256 rows per block

    dual_compress_kernel<<<grid, 256, 0, stream>>>(
        d_out_t, d_in_t, alpha_fwd, alpha_bwd, out, V);
}

// Round 4
// 102.734 us; speedup vs baseline: 2.1571x; 2.1571x over previous
//
#include <hip/hip_runtime.h>

// DualCompressor: y_fwd[v,m] = log(sum_k exp(d_out_t[v,k] + alpha_fwd[m,k]))
//                 y_bwd[v,m] = log(sum_k exp(d_in_t[v,k]  + alpha_bwd[m,k]))
// SIGMA = 1.0.
//
// log(sum_k exp(phi_k)*exp(alpha_mk)): exp(alpha) in LDS, exp(phi) streamed,
// 16 FMA dot products per row.
//
// R3 change: keep 2 rows/thread (halves wave-uniform LDS issue vs R1's
// 15.6 us binder) but restructure k-OUTER so per-thread live state is just
// 32 scalar accumulators. R2's materialize-exp(phi)-first layout needed
// ~200 VGPRs -> hit the 256 cap -> ~290 MB of scratch spill traffic
// (WRITE_SIZE 222 MB, FETCH 129 MB) -> 156 us. Here loads stream through
// 8 float4 registers per unroll step (#pragma unroll 4 bounds in-flight
// loads to 32 VGPRs).
//
// Mapping: block 256 = 4 waves covering 256 rows; wave w: c = w&1
// (0=fwd, 1=bwd), rh = w>>1; rows v0 = bid*256 + rh*128 + lane, v1 = v0+64.
// All ealpha LDS reads wave-uniform -> HW broadcast, zero bank conflicts;
// each ds_read_b128 feeds 8 FMAs (4 k-components x 2 rows).

#define K_DIM 64

__global__ __launch_bounds__(256) void dual_compress_kernel(
    const float* __restrict__ d_out_t,
    const float* __restrict__ d_in_t,
    const float* __restrict__ alpha_fwd,
    const float* __restrict__ alpha_bwd,
    float* __restrict__ out, int V)
{
    // exp(alpha): [c][m][k], c=0 fwd rows 0..15, c=1 bwd rows 16..31
    __shared__ float ealpha[32 * K_DIM];

    int tid = threadIdx.x;
    #pragma unroll
    for (int it = 0; it < 8; ++it) {
        int i = tid + it * 256;                       // 0..2047
        float a = (i < 1024) ? alpha_fwd[i] : alpha_bwd[i - 1024];
        ealpha[i] = __expf(a);
    }
    __syncthreads();

    int lane = tid & 63;
    int w    = tid >> 6;        // wave id: 0..3
    int c    = w & 1;           // 0 = fwd (d_out_t), 1 = bwd (d_in_t)
    int rh   = w >> 1;          // row group within the block's 256 rows
    int v0   = blockIdx.x * 256 + rh * 128 + lane;
    int v1   = v0 + 64;
    if (v0 >= V) return;
    bool has1 = (v1 < V);

    const float* base = (c == 0) ? d_out_t : d_in_t;
    const float4* p0 = (const float4*)(base + (size_t)v0 * K_DIM);
    const float4* p1 = (const float4*)(base + (size_t)(has1 ? v1 : v0) * K_DIM);

    const float4* arow = (const float4*)&ealpha[c * 16 * K_DIM];

    float acc0[16], acc1[16];
    #pragma unroll
    for (int mi = 0; mi < 16; ++mi) { acc0[mi] = 0.0f; acc1[mi] = 0.0f; }

    // k-outer: stream phi chunks, accumulate into 32 registers.
    #pragma unroll 4
    for (int kc = 0; kc < 16; ++kc) {
        float4 q0 = p0[kc];
        float4 q1 = p1[kc];
        float4 e0, e1;
        e0.x = __expf(q0.x); e0.y = __expf(q0.y);
        e0.z = __expf(q0.z); e0.w = __expf(q0.w);
        e1.x = __expf(q1.x); e1.y = __expf(q1.y);
        e1.z = __expf(q1.z); e1.w = __expf(q1.w);

        #pragma unroll
        for (int mi = 0; mi < 16; ++mi) {
            float4 a = arow[mi * 16 + kc];   // wave-uniform -> broadcast
            acc0[mi] = fmaf(e0.x, a.x, acc0[mi]);
            acc0[mi] = fmaf(e0.y, a.y, acc0[mi]);
            acc0[mi] = fmaf(e0.z, a.z, acc0[mi]);
            acc0[mi] = fmaf(e0.w, a.w, acc0[mi]);
            acc1[mi] = fmaf(e1.x, a.x, acc1[mi]);
            acc1[mi] = fmaf(e1.y, a.y, acc1[mi]);
            acc1[mi] = fmaf(e1.z, a.z, acc1[mi]);
            acc1[mi] = fmaf(e1.w, a.w, acc1[mi]);
        }
    }

    // logs + stores: y_fwd (V x 16) then y_bwd (V x 16)
    float* orow0 = out + ((size_t)c * V + v0) * 16;
    #pragma unroll
    for (int i = 0; i < 4; ++i) {
        float4 y;
        y.x = __logf(acc0[4*i+0]);
        y.y = __logf(acc0[4*i+1]);
        y.z = __logf(acc0[4*i+2]);
        y.w = __logf(acc0[4*i+3]);
        ((float4*)orow0)[i] = y;
    }

    if (has1) {
        float* orow1 = out + ((size_t)c * V + v1) * 16;
        #pragma unroll
        for (int i = 0; i < 4; ++i) {
            float4 y;
            y.x = __logf(acc1[4*i+0]);
            y.y = __logf(acc1[4*i+1]);
            y.z = __logf(acc1[4*i+2]);
            y.w = __logf(acc1[4*i+3]);
            ((float4*)orow1)[i] = y;
        }
    }
}

extern "C" void kernel_launch(void* const* d_in, const int* in_sizes, int n_in,
                              void* d_out, int out_size, void* d_ws, size_t ws_size,
                              hipStream_t stream) {
    const float* d_out_t   = (const float*)d_in[0];
    const float* d_in_t    = (const float*)d_in[1];
    const float* alpha_fwd = (const float*)d_in[2];
    const float* alpha_bwd = (const float*)d_in[3];
    float* out = (float*)d_out;

    int V = in_sizes[0] / K_DIM;          // 100000
    int grid = (V + 255) / 256;           // 256 rows per block

    dual_compress_kernel<<<grid, 256, 0, stream>>>(
        d_out_t, d_in_t, alpha_fwd, alpha_bwd, out, V);
}

// Round 5
// 101.549 us; speedup vs baseline: 2.1823x; 1.0117x over previous
//
#include <hip/hip_runtime.h>

// DualCompressor: y_fwd[v,m] = log(sum_k exp(d_out_t[v,k] + alpha_fwd[m,k]))
//                 y_bwd[v,m] = log(sum_k exp(d_in_t[v,k]  + alpha_bwd[m,k]))
// SIGMA = 1.0.
//
// log(sum_k exp(phi_k)*exp(alpha_mk)). R5 change: the alpha operand is
// wave-uniform (lane = row), so keep exp(alpha) in SGPRs, not LDS.
// R2-best (1 row/thread, LDS broadcast) was LDS-issue-bound: 256
// ds_read_b128/row x 12 cyc x 12.2 waves/CU = 15.6 us/CU. R4 (2 rows/thread)
// halved LDS but halved occupancy -> latency-bound, net regression.
// Here: a prep kernel writes exp(alpha) (2048 floats) to d_ws; the main
// kernel indexes it with provably-uniform indices (readfirstlane + unrolled
// constants, no divergent CF before the loads) so the compiler emits
// s_load_dwordx16 through the scalar cache, and the inner loop is pure
// v_fmac_f32 with an SGPR source. LDS cost -> 0; binder becomes HBM
// (64 MB @ 6.3 TB/s ~ 10.2 us).
//
// Mapping: block 256 = 4 waves over 128 rows; wave w: c = w&1 (0=fwd,1=bwd),
// rh = w>>1. v is CLAMPED (not early-returned) to keep control flow uniform
// so the scalar loads stay scalar; only the store is guarded.

#define K_DIM 64

__global__ __launch_bounds__(256) void prep_ealpha_kernel(
    const float* __restrict__ alpha_fwd,
    const float* __restrict__ alpha_bwd,
    float* __restrict__ ea)
{
    int i = blockIdx.x * 256 + threadIdx.x;       // grid 8 -> i in 0..2047
    float a = (i < 1024) ? alpha_fwd[i] : alpha_bwd[i - 1024];
    ea[i] = __expf(a);
}

__global__ __launch_bounds__(256) void dual_compress_kernel(
    const float* __restrict__ d_out_t,
    const float* __restrict__ d_in_t,
    const float* __restrict__ ea,     // exp(alpha): [c][m][k], 2048 floats
    float* __restrict__ out, int V)
{
    int tid  = threadIdx.x;
    int lane = tid & 63;
    int w    = tid >> 6;        // wave id: 0..3
    int c    = w & 1;           // 0 = fwd (d_out_t), 1 = bwd (d_in_t)
    int rh   = w >> 1;          // row half within the block's 128 rows
    int v    = blockIdx.x * 128 + rh * 64 + lane;
    int vc   = (v < V) ? v : (V - 1);             // clamp: uniform CF

    const float* base = c ? d_in_t : d_out_t;
    const float4* p = (const float4*)(base + (size_t)vc * K_DIM);

    // exp(phi row) into registers (16 x float4 = 64 VGPRs)
    float4 e4[16];
    #pragma unroll
    for (int i = 0; i < 16; ++i) {
        float4 q = p[i];
        e4[i].x = __expf(q.x); e4[i].y = __expf(q.y);
        e4[i].z = __expf(q.z); e4[i].w = __expf(q.w);
    }

    // wave-uniform base into the exp(alpha) table -> scalar loads
    const float* eac = ea + __builtin_amdgcn_readfirstlane(c << 10);

    float acc[16];
    #pragma unroll
    for (int mi = 0; mi < 16; ++mi) acc[mi] = 0.0f;

    // 1024 v_fmac with SGPR alpha operand; 16 independent acc chains.
    #pragma unroll
    for (int kc = 0; kc < 16; ++kc) {
        float4 e = e4[kc];
        #pragma unroll
        for (int mi = 0; mi < 16; ++mi) {
            const float* arow = eac + mi * K_DIM + kc * 4;
            acc[mi] = fmaf(e.x, arow[0], acc[mi]);
            acc[mi] = fmaf(e.y, arow[1], acc[mi]);
            acc[mi] = fmaf(e.z, arow[2], acc[mi]);
            acc[mi] = fmaf(e.w, arow[3], acc[mi]);
        }
    }

    if (v < V) {
        float* orow = out + ((size_t)c * V + v) * 16;
        #pragma unroll
        for (int i = 0; i < 4; ++i) {
            float4 y;
            y.x = __logf(acc[4*i+0]);
            y.y = __logf(acc[4*i+1]);
            y.z = __logf(acc[4*i+2]);
            y.w = __logf(acc[4*i+3]);
            ((float4*)orow)[i] = y;
        }
    }
}

extern "C" void kernel_launch(void* const* d_in, const int* in_sizes, int n_in,
                              void* d_out, int out_size, void* d_ws, size_t ws_size,
                              hipStream_t stream) {
    const float* d_out_t   = (const float*)d_in[0];
    const float* d_in_t    = (const float*)d_in[1];
    const float* alpha_fwd = (const float*)d_in[2];
    const float* alpha_bwd = (const float*)d_in[3];
    float* out = (float*)d_out;
    float* ea  = (float*)d_ws;            // 2048 floats of scratch

    int V = in_sizes[0] / K_DIM;          // 100000

    prep_ealpha_kernel<<<8, 256, 0, stream>>>(alpha_fwd, alpha_bwd, ea);

    int grid = (V + 127) / 128;           // 128 rows per block
    dual_compress_kernel<<<grid, 256, 0, stream>>>(
        d_out_t, d_in_t, ea, out, V);
}